// Round 4
// baseline (268.918 us; speedup 1.0000x reference)
//
#include <hip/hip_runtime.h>
#include <stdint.h>

typedef __attribute__((ext_vector_type(8))) short short8;
typedef __attribute__((ext_vector_type(4))) float f32x4;

#define BH 96
#define T 1024
#define D 256

static __device__ __forceinline__ unsigned short f2bf(float x){
  uint32_t u = __float_as_uint(x);
  uint32_t r = (u + 0x7FFFu + ((u >> 16) & 1u)) >> 16;  // RNE
  return (unsigned short)r;
}

static __device__ __forceinline__ uint32_t cvtpk_bf16(float lo, float hi){
  uint32_t r;
  asm("v_cvt_pk_bf16_f32 %0, %1, %2" : "=v"(r) : "v"(lo), "v"(hi));
  return r;
}

static __device__ __forceinline__ float exp2_fast(float x){
  float r;
  asm("v_exp_f32 %0, %1" : "=v"(r) : "v"(x));
  return r;
}

static __device__ __forceinline__ void gload_lds16(const void* g, void* l){
  __builtin_amdgcn_global_load_lds((const __attribute__((address_space(1))) void*)g,
                                   (__attribute__((address_space(3))) void*)l, 16, 0, 0);
}

// ---------------- Kernel 1: RoPE + (0.25*sqrt(log2e)) scale + bf16 cast
__global__ void k_rope(const float* __restrict__ Q, const float* __restrict__ freqs,
                       unsigned short* __restrict__ QR){
  const float SC = 0.25f * 1.20112241f;   // 0.25 * sqrt(log2(e)) -> scores in log2 domain
  long idx = (long)blockIdx.x * 256 + threadIdx.x;
  long e = idx * 4;
  int n = (int)(e & (D - 1));
  int t = (int)((e >> 8) & (T - 1));
  float4 q = *(const float4*)(Q + e);
  float f0 = freqs[n];
  float f2 = freqs[n + 2];
  float ph0 = (float)t * f0; ph0 -= floorf(ph0);
  float ph2 = (float)t * f2; ph2 -= floorf(ph2);
  float c0 = __builtin_amdgcn_cosf(ph0), s0 = __builtin_amdgcn_sinf(ph0);
  float c2 = __builtin_amdgcn_cosf(ph2), s2 = __builtin_amdgcn_sinf(ph2);
  float o0 = (q.x * c0 - q.y * s0) * SC;
  float o1 = (q.y * c0 + q.x * s0) * SC;
  float o2 = (q.z * c2 - q.w * s2) * SC;
  float o3 = (q.w * c2 + q.z * s2) * SC;
  ushort4 o;
  o.x = f2bf(o0); o.y = f2bf(o1); o.z = f2bf(o2); o.w = f2bf(o3);
  *(ushort4*)(QR + e) = o;
}

// ---------------- Kernel 2: V [bh][t][n] fp32 -> Vt [bh][n][t] bf16
__global__ void k_transpose(const float* __restrict__ V, unsigned short* __restrict__ Vt){
  __shared__ unsigned short L[64 * 66];
  int bid = blockIdx.x;
  int head = bid >> 6;
  int rem = bid & 63;
  int t0 = (rem & 15) * 64;
  int n0 = (rem >> 4) * 64;
  int tid = threadIdx.x;
  const float* Vh = V + (long)head * T * D;
  unsigned short* Vth = Vt + (long)head * T * D;
  int lr = tid >> 4;
  int lc = (tid & 15) * 4;
#pragma unroll
  for (int i = 0; i < 4; ++i){
    int tl = i * 16 + lr;
    float4 v = *(const float4*)(Vh + (long)(t0 + tl) * D + n0 + lc);
    uint32_t w0 = (uint32_t)f2bf(v.x) | ((uint32_t)f2bf(v.y) << 16);
    uint32_t w1 = (uint32_t)f2bf(v.z) | ((uint32_t)f2bf(v.w) << 16);
    *(uint32_t*)&L[tl * 66 + lc]     = w0;
    *(uint32_t*)&L[tl * 66 + lc + 2] = w1;
  }
  __syncthreads();
  int nr = tid >> 3;
  int t8 = (tid & 7) * 8;
#pragma unroll
  for (int i = 0; i < 2; ++i){
    int n_row = i * 32 + nr;
    unsigned short u[8];
#pragma unroll
    for (int j = 0; j < 8; ++j) u[j] = L[(t8 + j) * 66 + n_row];
    uint4 o;
    o.x = (uint32_t)u[0] | ((uint32_t)u[1] << 16);
    o.y = (uint32_t)u[2] | ((uint32_t)u[3] << 16);
    o.z = (uint32_t)u[4] | ((uint32_t)u[5] << 16);
    o.w = (uint32_t)u[6] | ((uint32_t)u[7] << 16);
    *(uint4*)(Vth + (long)(n0 + n_row) * T + t0 + t8) = o;
  }
}

// exp2 + per-lane partial sum + bf16 pack + redistribute into PV B-fragment layout
static __device__ __forceinline__ short8 packP(f32x4 st0, f32x4 st1, float m, float& lsum,
                                               int q15, int g){
  float p00 = exp2_fast(st0.x - m), p01 = exp2_fast(st0.y - m);
  float p02 = exp2_fast(st0.z - m), p03 = exp2_fast(st0.w - m);
  float p10 = exp2_fast(st1.x - m), p11 = exp2_fast(st1.y - m);
  float p12 = exp2_fast(st1.z - m), p13 = exp2_fast(st1.w - m);
  lsum += ((p00 + p01) + (p02 + p03)) + ((p10 + p11) + (p12 + p13));  // per-lane partial
  uint32_t t0w0 = cvtpk_bf16(p00, p01), t0w1 = cvtpk_bf16(p02, p03);
  uint32_t t1w0 = cvtpk_bf16(p10, p11), t1w1 = cvtpk_bf16(p12, p13);
  int s0l = ((g & 1) << 5) | q15;
  int s1l = s0l + 16;
  uint32_t x0 = __shfl(t0w0, s0l), x1 = __shfl(t0w1, s0l);
  uint32_t X0 = __shfl(t1w0, s0l), X1 = __shfl(t1w1, s0l);
  uint32_t y0 = __shfl(t0w0, s1l), y1 = __shfl(t0w1, s1l);
  uint32_t Y0 = __shfl(t1w0, s1l), Y1 = __shfl(t1w1, s1l);
  bool lo = (g < 2);
  uint4 aws;
  aws.x = lo ? x0 : X0;
  aws.y = lo ? x1 : X1;
  aws.z = lo ? y0 : Y0;
  aws.w = lo ? y1 : Y1;
  return __builtin_bit_cast(short8, aws);
}

// combined softmax for both q-subtiles; acc-rescale happens here (callers place
// this AFTER the deferred PV so the ordering acc += P(t-1)V(t-1); acc *= alpha holds)
static __device__ __forceinline__ void softmax2(
    f32x4 s0a, f32x4 s1a, f32x4 s0b, f32x4 s1b,
    float& mA, float& mB, float& lA, float& lB,
    f32x4* accA, f32x4* accB, short8& paA, short8& paB, int q15, int g){
  float lmA = fmaxf(fmaxf(fmaxf(s0a.x, s0a.y), fmaxf(s0a.z, s0a.w)),
                    fmaxf(fmaxf(s1a.x, s1a.y), fmaxf(s1a.z, s1a.w)));
  float lmB = fmaxf(fmaxf(fmaxf(s0b.x, s0b.y), fmaxf(s0b.z, s0b.w)),
                    fmaxf(fmaxf(s1b.x, s1b.y), fmaxf(s1b.z, s1b.w)));
  if (__any((lmA > mA + 11.0f) || (lmB > mB + 11.0f))){   // defer-max (log2 units)
    float tmA = fmaxf(lmA, __shfl_xor(lmA, 16)); tmA = fmaxf(tmA, __shfl_xor(tmA, 32));
    float tmB = fmaxf(lmB, __shfl_xor(lmB, 16)); tmB = fmaxf(tmB, __shfl_xor(tmB, 32));
    float mnA = fmaxf(mA, tmA), mnB = fmaxf(mB, tmB);
    float aA = exp2_fast(mA - mnA), aB = exp2_fast(mB - mnB);
    mA = mnA; mB = mnB;
    lA *= aA; lB *= aB;
#pragma unroll
    for (int nc = 0; nc < 16; ++nc){ accA[nc] *= aA; accB[nc] *= aB; }  // per-lane scalar!
  }
  paA = packP(s0a, s1a, mA, lA, q15, g);
  paB = packP(s0b, s1b, mB, lB, q15, g);
}

// ---------------- Kernel 3: flash attention, T15 P-deferral pipeline.
// Step t: issue K(t+1)/V(t) DMA; QK(t); PV(t-1) MFMAs interleaved with softmax(t) VALU.
// PV in O^T form: acc = mfma(Vt_frag, P_frag) -> lane owns its query in all 4 acc regs.
__global__ __launch_bounds__(256, 2) void k_flash(const unsigned short* __restrict__ QR,
                                                  const unsigned short* __restrict__ Vt,
                                                  float* __restrict__ Out){
  __shared__ short lds[4][8192];   // [0..1] K double-buffer, [2..3] V double-buffer
  int tid = threadIdx.x;
  int wid = tid >> 6, lane = tid & 63;
  int q15 = lane & 15, g = lane >> 4;

  int b = blockIdx.x;
  int x = b & 7, s = b >> 3;
  int qt = s & 7, hg = s >> 3;
  int head = hg * 8 + x;            // XCD-bijective: one head's 8 q-blocks per XCD

  const unsigned short* qr = QR + (long)head * T * D;
  const unsigned short* vt = Vt + (long)head * T * D;
  int qb = qt * 128 + wid * 32;

  int bK[4], bV[4];
#pragma unroll
  for (int j = 0; j < 4; ++j){
    int i = tid + j * 256;
    bK[j] = (((i >> 9) * 16 + (i & 15)) * 256) + ((i >> 6) & 7) * 32 + ((i >> 4) & 3) * 8;
    bV[j] = ((i >> 6) * 16 + (i & 15)) * 1024 + ((i >> 4) & 3) * 8;
  }

  short8 qfA[8], qfB[8];
#pragma unroll
  for (int c = 0; c < 8; ++c){
    qfA[c] = *(const short8*)(qr + (long)(qb + q15) * D + c * 32 + g * 8);
    qfB[c] = *(const short8*)(qr + (long)(qb + 16 + q15) * D + c * 32 + g * 8);
  }

  f32x4 accA[16], accB[16];
#pragma unroll
  for (int i = 0; i < 16; ++i){
    accA[i] = f32x4{0.f, 0.f, 0.f, 0.f};
    accB[i] = f32x4{0.f, 0.f, 0.f, 0.f};
  }
  float mA = -3e38f, mB = -3e38f, lA = 0.f, lB = 0.f;
  short8 paA, paB;

  // prologue: stage K(0)
#pragma unroll
  for (int j = 0; j < 4; ++j){
    int i = tid + j * 256;
    gload_lds16(qr + bK[j], &lds[0][i * 8]);
  }
  asm volatile("s_waitcnt vmcnt(0)" ::: "memory");
  __syncthreads();

  // step 0: QK(0) + softmax(0); stage K(1), V(0)
  {
#pragma unroll
    for (int j = 0; j < 4; ++j){
      int i = tid + j * 256;
      gload_lds16(qr + 32 * 256 + bK[j], &lds[1][i * 8]);
      gload_lds16(vt + bV[j],            &lds[2][i * 8]);
    }
    const short* ldsK = lds[0];
    f32x4 s0a = f32x4{0.f,0.f,0.f,0.f}, s0b = f32x4{0.f,0.f,0.f,0.f};
    f32x4 s1a = f32x4{0.f,0.f,0.f,0.f}, s1b = f32x4{0.f,0.f,0.f,0.f};
    __builtin_amdgcn_s_setprio(1);
#pragma unroll
    for (int c = 0; c < 8; ++c){
      short8 kf0 = *(const short8*)&ldsK[c * 512 + lane * 8];
      short8 kf1 = *(const short8*)&ldsK[4096 + c * 512 + lane * 8];
      s0a = __builtin_amdgcn_mfma_f32_16x16x32_bf16(kf0, qfA[c], s0a, 0, 0, 0);
      s0b = __builtin_amdgcn_mfma_f32_16x16x32_bf16(kf0, qfB[c], s0b, 0, 0, 0);
      s1a = __builtin_amdgcn_mfma_f32_16x16x32_bf16(kf1, qfA[c], s1a, 0, 0, 0);
      s1b = __builtin_amdgcn_mfma_f32_16x16x32_bf16(kf1, qfB[c], s1b, 0, 0, 0);
    }
    __builtin_amdgcn_s_setprio(0);
    softmax2(s0a, s1a, s0b, s1b, mA, mB, lA, lB, accA, accB, paA, paB, q15, g);
    asm volatile("s_waitcnt vmcnt(0)" ::: "memory");
    __syncthreads();
  }

  for (int t = 1; t < 32; ++t){
    int kb = t << 5;
    {   // issue K(t+1) and V(t) DMA (K(32) reads harmlessly into adjacent ws region)
      const unsigned short* sk = qr + (long)(kb + 32) * 256;
      const unsigned short* sv = vt + kb;
      short* kd = lds[(t + 1) & 1];
      short* vd = lds[2 + (t & 1)];
#pragma unroll
      for (int j = 0; j < 4; ++j){
        int i = tid + j * 256;
        gload_lds16(sk + bK[j], kd + i * 8);
        gload_lds16(sv + bV[j], vd + i * 8);
      }
    }
    const short* ldsK = lds[t & 1];
    f32x4 s0a = f32x4{0.f,0.f,0.f,0.f}, s0b = f32x4{0.f,0.f,0.f,0.f};
    f32x4 s1a = f32x4{0.f,0.f,0.f,0.f}, s1b = f32x4{0.f,0.f,0.f,0.f};
    __builtin_amdgcn_s_setprio(1);
#pragma unroll
    for (int c = 0; c < 8; ++c){
      short8 kf0 = *(const short8*)&ldsK[c * 512 + lane * 8];
      short8 kf1 = *(const short8*)&ldsK[4096 + c * 512 + lane * 8];
      s0a = __builtin_amdgcn_mfma_f32_16x16x32_bf16(kf0, qfA[c], s0a, 0, 0, 0);
      s0b = __builtin_amdgcn_mfma_f32_16x16x32_bf16(kf0, qfB[c], s0b, 0, 0, 0);
      s1a = __builtin_amdgcn_mfma_f32_16x16x32_bf16(kf1, qfA[c], s1a, 0, 0, 0);
      s1b = __builtin_amdgcn_mfma_f32_16x16x32_bf16(kf1, qfB[c], s1b, 0, 0, 0);
    }
    // PV(t-1) — independent of softmax(t) below; compiler interleaves MFMA & VALU
    const short* ldsVp = lds[2 + ((t - 1) & 1)];
#pragma unroll
    for (int nc = 0; nc < 16; ++nc){
      short8 vf = *(const short8*)&ldsVp[nc * 512 + lane * 8];
      accA[nc] = __builtin_amdgcn_mfma_f32_16x16x32_bf16(vf, paA, accA[nc], 0, 0, 0);
      accB[nc] = __builtin_amdgcn_mfma_f32_16x16x32_bf16(vf, paB, accB[nc], 0, 0, 0);
    }
    __builtin_amdgcn_s_setprio(0);
    softmax2(s0a, s1a, s0b, s1b, mA, mB, lA, lB, accA, accB, paA, paB, q15, g);
    asm volatile("s_waitcnt vmcnt(0)" ::: "memory");
    __syncthreads();
  }

  // epilogue: PV(31)
  {
    const short* ldsVp = lds[3];
    __builtin_amdgcn_s_setprio(1);
#pragma unroll
    for (int nc = 0; nc < 16; ++nc){
      short8 vf = *(const short8*)&ldsVp[nc * 512 + lane * 8];
      accA[nc] = __builtin_amdgcn_mfma_f32_16x16x32_bf16(vf, paA, accA[nc], 0, 0, 0);
      accB[nc] = __builtin_amdgcn_mfma_f32_16x16x32_bf16(vf, paB, accB[nc], 0, 0, 0);
    }
    __builtin_amdgcn_s_setprio(0);
  }

  lA += __shfl_xor(lA, 16); lA += __shfl_xor(lA, 32);
  lB += __shfl_xor(lB, 16); lB += __shfl_xor(lB, 32);
  float rA = 1.0f / lA, rB = 1.0f / lB;
  float* opA = Out + (long)head * T * D + (long)(qb + q15) * D + g * 4;
  float* opB = opA + 16 * D;
#pragma unroll
  for (int nc = 0; nc < 16; ++nc){
    f32x4 oa = accA[nc] * rA;
    f32x4 ob = accB[nc] * rB;
    *(f32x4*)(opA + nc * 16) = oa;   // contiguous float4 per lane
    *(f32x4*)(opB + nc * 16) = ob;
  }
}

extern "C" void kernel_launch(void* const* d_in, const int* in_sizes, int n_in,
                              void* d_out, int out_size, void* d_ws, size_t ws_size,
                              hipStream_t stream){
  (void)in_sizes; (void)n_in; (void)out_size; (void)ws_size;
  const float* Q     = (const float*)d_in[0];
  const float* V     = (const float*)d_in[1];
  const float* freqs = (const float*)d_in[2];
  float* Out = (float*)d_out;
  unsigned short* QR = (unsigned short*)d_ws;                  // [96][1024][256] bf16
  unsigned short* Vt = QR + (size_t)BH * T * D;                // [96][256][1024] bf16
  k_rope<<<dim3((BH * T * D) / 4 / 256), dim3(256), 0, stream>>>(Q, freqs, QR);
  k_transpose<<<dim3(BH * 64), dim3(256), 0, stream>>>(V, Vt);
  k_flash<<<dim3(BH * 8), dim3(256), 0, stream>>>(QR, Vt, Out);
}

// Round 5
// 190.458 us; speedup vs baseline: 1.4120x; 1.4120x over previous
//
#include <hip/hip_runtime.h>
#include <stdint.h>

typedef __attribute__((ext_vector_type(8))) short short8;
typedef __attribute__((ext_vector_type(4))) float f32x4;

#define BH 96
#define T 1024
#define D 256

static __device__ __forceinline__ unsigned short f2bf(float x){
  uint32_t u = __float_as_uint(x);
  uint32_t r = (u + 0x7FFFu + ((u >> 16) & 1u)) >> 16;  // RNE
  return (unsigned short)r;
}

static __device__ __forceinline__ uint32_t cvtpk_bf16(float lo, float hi){
  uint32_t r;
  asm("v_cvt_pk_bf16_f32 %0, %1, %2" : "=v"(r) : "v"(lo), "v"(hi));
  return r;
}

static __device__ __forceinline__ float exp2_fast(float x){
  float r;
  asm("v_exp_f32 %0, %1" : "=v"(r) : "v"(x));
  return r;
}

static __device__ __forceinline__ void gload_lds16(const void* g, void* l){
  __builtin_amdgcn_global_load_lds((const __attribute__((address_space(1))) void*)g,
                                   (__attribute__((address_space(3))) void*)l, 16, 0, 0);
}

// ---------------- Kernel 1: RoPE + (0.25*sqrt(log2e)) scale + bf16 cast
__global__ void k_rope(const float* __restrict__ Q, const float* __restrict__ freqs,
                       unsigned short* __restrict__ QR){
  const float SC = 0.25f * 1.20112241f;   // 0.25 * sqrt(log2(e)) -> scores in log2 domain
  long idx = (long)blockIdx.x * 256 + threadIdx.x;
  long e = idx * 4;
  int n = (int)(e & (D - 1));
  int t = (int)((e >> 8) & (T - 1));
  float4 q = *(const float4*)(Q + e);
  float f0 = freqs[n];
  float f2 = freqs[n + 2];
  float ph0 = (float)t * f0; ph0 -= floorf(ph0);
  float ph2 = (float)t * f2; ph2 -= floorf(ph2);
  float c0 = __builtin_amdgcn_cosf(ph0), s0 = __builtin_amdgcn_sinf(ph0);
  float c2 = __builtin_amdgcn_cosf(ph2), s2 = __builtin_amdgcn_sinf(ph2);
  float o0 = (q.x * c0 - q.y * s0) * SC;
  float o1 = (q.y * c0 + q.x * s0) * SC;
  float o2 = (q.z * c2 - q.w * s2) * SC;
  float o3 = (q.w * c2 + q.z * s2) * SC;
  ushort4 o;
  o.x = f2bf(o0); o.y = f2bf(o1); o.z = f2bf(o2); o.w = f2bf(o3);
  *(ushort4*)(QR + e) = o;
}

// ---------------- Kernel 2: V [bh][t][n] fp32 -> Vt [bh][n][t] bf16
__global__ void k_transpose(const float* __restrict__ V, unsigned short* __restrict__ Vt){
  __shared__ unsigned short L[64 * 66];
  int bid = blockIdx.x;
  int head = bid >> 6;
  int rem = bid & 63;
  int t0 = (rem & 15) * 64;
  int n0 = (rem >> 4) * 64;
  int tid = threadIdx.x;
  const float* Vh = V + (long)head * T * D;
  unsigned short* Vth = Vt + (long)head * T * D;
  int lr = tid >> 4;
  int lc = (tid & 15) * 4;
#pragma unroll
  for (int i = 0; i < 4; ++i){
    int tl = i * 16 + lr;
    float4 v = *(const float4*)(Vh + (long)(t0 + tl) * D + n0 + lc);
    uint32_t w0 = (uint32_t)f2bf(v.x) | ((uint32_t)f2bf(v.y) << 16);
    uint32_t w1 = (uint32_t)f2bf(v.z) | ((uint32_t)f2bf(v.w) << 16);
    *(uint32_t*)&L[tl * 66 + lc]     = w0;
    *(uint32_t*)&L[tl * 66 + lc + 2] = w1;
  }
  __syncthreads();
  int nr = tid >> 3;
  int t8 = (tid & 7) * 8;
#pragma unroll
  for (int i = 0; i < 2; ++i){
    int n_row = i * 32 + nr;
    unsigned short u[8];
#pragma unroll
    for (int j = 0; j < 8; ++j) u[j] = L[(t8 + j) * 66 + n_row];
    uint4 o;
    o.x = (uint32_t)u[0] | ((uint32_t)u[1] << 16);
    o.y = (uint32_t)u[2] | ((uint32_t)u[3] << 16);
    o.z = (uint32_t)u[4] | ((uint32_t)u[5] << 16);
    o.w = (uint32_t)u[6] | ((uint32_t)u[7] << 16);
    *(uint4*)(Vth + (long)(n0 + n_row) * T + t0 + t8) = o;
  }
}

// exp2 + per-lane partial sum + bf16 pack + redistribute. Output register contents
// serve as PV's B-fragment (A-frag of P == B-frag of P^T, same lane map).
static __device__ __forceinline__ short8 packP(f32x4 st0, f32x4 st1, float m, float& lsum,
                                               int q15, int g){
  float p00 = exp2_fast(st0.x - m), p01 = exp2_fast(st0.y - m);
  float p02 = exp2_fast(st0.z - m), p03 = exp2_fast(st0.w - m);
  float p10 = exp2_fast(st1.x - m), p11 = exp2_fast(st1.y - m);
  float p12 = exp2_fast(st1.z - m), p13 = exp2_fast(st1.w - m);
  lsum += ((p00 + p01) + (p02 + p03)) + ((p10 + p11) + (p12 + p13));  // per-lane partial
  uint32_t t0w0 = cvtpk_bf16(p00, p01), t0w1 = cvtpk_bf16(p02, p03);
  uint32_t t1w0 = cvtpk_bf16(p10, p11), t1w1 = cvtpk_bf16(p12, p13);
  int s0l = ((g & 1) << 5) | q15;
  int s1l = s0l + 16;
  uint32_t x0 = __shfl(t0w0, s0l), x1 = __shfl(t0w1, s0l);
  uint32_t X0 = __shfl(t1w0, s0l), X1 = __shfl(t1w1, s0l);
  uint32_t y0 = __shfl(t0w0, s1l), y1 = __shfl(t0w1, s1l);
  uint32_t Y0 = __shfl(t1w0, s1l), Y1 = __shfl(t1w1, s1l);
  bool lo = (g < 2);
  uint4 aws;
  aws.x = lo ? x0 : X0;
  aws.y = lo ? x1 : X1;
  aws.z = lo ? y0 : Y0;
  aws.w = lo ? y1 : Y1;
  return __builtin_bit_cast(short8, aws);
}

// merged softmax for both q-subtiles; O^T acc form -> rescale is per-lane scalar
static __device__ __forceinline__ void softmax2(
    f32x4 s0a, f32x4 s1a, f32x4 s0b, f32x4 s1b,
    float& mA, float& mB, float& lA, float& lB,
    f32x4* accA, f32x4* accB, short8& paA, short8& paB, int q15, int g){
  float lmA = fmaxf(fmaxf(fmaxf(s0a.x, s0a.y), fmaxf(s0a.z, s0a.w)),
                    fmaxf(fmaxf(s1a.x, s1a.y), fmaxf(s1a.z, s1a.w)));
  float lmB = fmaxf(fmaxf(fmaxf(s0b.x, s0b.y), fmaxf(s0b.z, s0b.w)),
                    fmaxf(fmaxf(s1b.x, s1b.y), fmaxf(s1b.z, s1b.w)));
  if (__any((lmA > mA + 11.0f) || (lmB > mB + 11.0f))){   // defer-max (log2 units)
    float tmA = fmaxf(lmA, __shfl_xor(lmA, 16)); tmA = fmaxf(tmA, __shfl_xor(tmA, 32));
    float tmB = fmaxf(lmB, __shfl_xor(lmB, 16)); tmB = fmaxf(tmB, __shfl_xor(tmB, 32));
    float mnA = fmaxf(mA, tmA), mnB = fmaxf(mB, tmB);
    float aA = exp2_fast(mA - mnA), aB = exp2_fast(mB - mnB);
    mA = mnA; mB = mnB;
    lA *= aA; lB *= aB;
#pragma unroll
    for (int nc = 0; nc < 16; ++nc){ accA[nc] *= aA; accB[nc] *= aB; }  // per-lane scalar
  }
  paA = packP(s0a, s1a, mA, lA, q15, g);
  paB = packP(s0b, s1b, mB, lB, q15, g);
}

// ---------------- Kernel 3: flash attention, R3 control flow + O^T PV epilogue.
// 4 waves x 32 q-rows (q-tile 128), KTILE=32, double-buffered LDS (64KB).
__global__ __launch_bounds__(256, 2) void k_flash(const unsigned short* __restrict__ QR,
                                                  const unsigned short* __restrict__ Vt,
                                                  float* __restrict__ Out){
  __shared__ short lds[2][16384];   // [buf][ K:0..8191 | V:8192..16383 ]
  int tid = threadIdx.x;
  int wid = tid >> 6, lane = tid & 63;
  int q15 = lane & 15, g = lane >> 4;

  int b = blockIdx.x;
  int x = b & 7, s = b >> 3;
  int qt = s & 7, hg = s >> 3;
  int head = hg * 8 + x;            // XCD-bijective: one head's 8 q-blocks per XCD

  const unsigned short* qr = QR + (long)head * T * D;
  const unsigned short* vt = Vt + (long)head * T * D;
  int qb = qt * 128 + wid * 32;

  int bK[4], bV[4];
#pragma unroll
  for (int j = 0; j < 4; ++j){
    int i = tid + j * 256;
    bK[j] = (((i >> 9) * 16 + (i & 15)) * 256) + ((i >> 6) & 7) * 32 + ((i >> 4) & 3) * 8;
    bV[j] = ((i >> 6) * 16 + (i & 15)) * 1024 + ((i >> 4) & 3) * 8;
  }

  short8 qfA[8], qfB[8];
#pragma unroll
  for (int c = 0; c < 8; ++c){
    qfA[c] = *(const short8*)(qr + (long)(qb + q15) * D + c * 32 + g * 8);
    qfB[c] = *(const short8*)(qr + (long)(qb + 16 + q15) * D + c * 32 + g * 8);
  }

  f32x4 accA[16], accB[16];
#pragma unroll
  for (int i = 0; i < 16; ++i){
    accA[i] = f32x4{0.f, 0.f, 0.f, 0.f};
    accB[i] = f32x4{0.f, 0.f, 0.f, 0.f};
  }
  float mA = -3e38f, mB = -3e38f, lA = 0.f, lB = 0.f;
  short8 paA, paB;

  // prologue: stage tile 0 into buf 0
#pragma unroll
  for (int j = 0; j < 4; ++j){
    int i = tid + j * 256;
    gload_lds16(qr + bK[j], &lds[0][i * 8]);
    gload_lds16(vt + bV[j], &lds[0][8192 + i * 8]);
  }
  asm volatile("s_waitcnt vmcnt(0)" ::: "memory");
  __syncthreads();

  int buf = 0;
  for (int kb = 0; kb < T; kb += 32){
    if (kb + 32 < T){
      const unsigned short* sk = qr + (long)(kb + 32) * 256;
      const unsigned short* sv = vt + (kb + 32);
#pragma unroll
      for (int j = 0; j < 4; ++j){
        int i = tid + j * 256;
        gload_lds16(sk + bK[j], &lds[buf ^ 1][i * 8]);
        gload_lds16(sv + bV[j], &lds[buf ^ 1][8192 + i * 8]);
      }
    }
    const short* ldsK = &lds[buf][0];
    const short* ldsV = &lds[buf][8192];

    f32x4 s0a = f32x4{0.f,0.f,0.f,0.f}, s0b = f32x4{0.f,0.f,0.f,0.f};
    f32x4 s1a = f32x4{0.f,0.f,0.f,0.f}, s1b = f32x4{0.f,0.f,0.f,0.f};
    __builtin_amdgcn_s_setprio(1);
#pragma unroll
    for (int c = 0; c < 8; ++c){
      short8 kf0 = *(const short8*)&ldsK[c * 512 + lane * 8];
      short8 kf1 = *(const short8*)&ldsK[4096 + c * 512 + lane * 8];
      s0a = __builtin_amdgcn_mfma_f32_16x16x32_bf16(kf0, qfA[c], s0a, 0, 0, 0);
      s0b = __builtin_amdgcn_mfma_f32_16x16x32_bf16(kf0, qfB[c], s0b, 0, 0, 0);
      s1a = __builtin_amdgcn_mfma_f32_16x16x32_bf16(kf1, qfA[c], s1a, 0, 0, 0);
      s1b = __builtin_amdgcn_mfma_f32_16x16x32_bf16(kf1, qfB[c], s1b, 0, 0, 0);
    }
    __builtin_amdgcn_s_setprio(0);
    softmax2(s0a, s1a, s0b, s1b, mA, mB, lA, lB, accA, accB, paA, paB, q15, g);
    __builtin_amdgcn_s_setprio(1);
#pragma unroll
    for (int nc = 0; nc < 16; ++nc){
      short8 vf = *(const short8*)&ldsV[nc * 512 + lane * 8];
      accA[nc] = __builtin_amdgcn_mfma_f32_16x16x32_bf16(vf, paA, accA[nc], 0, 0, 0);
      accB[nc] = __builtin_amdgcn_mfma_f32_16x16x32_bf16(vf, paB, accB[nc], 0, 0, 0);
    }
    __builtin_amdgcn_s_setprio(0);
    asm volatile("s_waitcnt vmcnt(0)" ::: "memory");
    __syncthreads();
    buf ^= 1;
  }

  // epilogue: O^T acc -> lane owns its own query; per-lane normalize, float4 stores
  lA += __shfl_xor(lA, 16); lA += __shfl_xor(lA, 32);
  lB += __shfl_xor(lB, 16); lB += __shfl_xor(lB, 32);
  float rA = 1.0f / lA, rB = 1.0f / lB;
  float* opA = Out + (long)head * T * D + (long)(qb + q15) * D + g * 4;
  float* opB = opA + 16 * D;
#pragma unroll
  for (int nc = 0; nc < 16; ++nc){
    f32x4 oa = accA[nc] * rA;
    f32x4 ob = accB[nc] * rB;
    *(f32x4*)(opA + nc * 16) = oa;
    *(f32x4*)(opB + nc * 16) = ob;
  }
}

extern "C" void kernel_launch(void* const* d_in, const int* in_sizes, int n_in,
                              void* d_out, int out_size, void* d_ws, size_t ws_size,
                              hipStream_t stream){
  (void)in_sizes; (void)n_in; (void)out_size; (void)ws_size;
  const float* Q     = (const float*)d_in[0];
  const float* V     = (const float*)d_in[1];
  const float* freqs = (const float*)d_in[2];
  float* Out = (float*)d_out;
  unsigned short* QR = (unsigned short*)d_ws;                  // [96][1024][256] bf16
  unsigned short* Vt = QR + (size_t)BH * T * D;                // [96][256][1024] bf16
  k_rope<<<dim3((BH * T * D) / 4 / 256), dim3(256), 0, stream>>>(Q, freqs, QR);
  k_transpose<<<dim3(BH * 64), dim3(256), 0, stream>>>(V, Vt);
  k_flash<<<dim3(BH * 8), dim3(256), 0, stream>>>(QR, Vt, Out);
}